// Round 8
// baseline (619.635 us; speedup 1.0000x reference)
//
#include <hip/hip_runtime.h>

// Self-attention block (non-local): B=8, C=256, H=W=64 -> N=4096, dk=64.
// out = x + gamma * softmax((Wq x)^T (Wk x) / 8) applied to (Wv x).
// Pipeline: prep (weights->bf16, fold log2e/8 into Wq) -> proj (MFMA GEMM,
// in-LDS transpose of x) -> flash (shared-P attention, m-block 64, kv-block
// 256).  R8: V and K stream L2->registers via inline-asm global_load_dwordx4
// (volatile: cannot be sunk or spilled mid-flight) with hand-counted
// s_waitcnt vmcnt(N) + sched_barrier(0) (rule-18).  V: 3-deep ring, 12 loads
// in flight steady-state; K(t+1) issued at ks5, drained by phase-1 vmcnt(0).
// P in double-buffered swizzled LDS (R4 geometry), 1 barrier/iter.

typedef __attribute__((ext_vector_type(8)))  short short8;
typedef __attribute__((ext_vector_type(4)))  short short4v;
typedef __attribute__((ext_vector_type(16))) float f32x16;
typedef __attribute__((ext_vector_type(4)))  float f32x4;

#define B_   8
#define C_   256
#define N_   4096
#define DK_  64
// log2(e) / sqrt(dk) = 1.4426950408889634 / 8
#define QSCL 0.18033688011112043f

#if defined(__has_builtin)
#if __has_builtin(__builtin_amdgcn_exp2f)
#define EXP2F(x) __builtin_amdgcn_exp2f(x)
#else
#define EXP2F(x) exp2f(x)
#endif
#else
#define EXP2F(x) exp2f(x)
#endif

// float -> bf16 bits, round-to-nearest-even (inputs are finite; no NaN path)
__device__ __forceinline__ unsigned short bfb(float f) {
  unsigned u = __builtin_bit_cast(unsigned, f);
  unsigned r = (u + 0x7fffu + ((u >> 16) & 1u)) >> 16;
  return (unsigned short)r;
}

// packed f32x2 -> bf16x2 (low = a, high = b), RNE
__device__ __forceinline__ unsigned cvtpk(float a, float b) {
  unsigned r;
  asm("v_cvt_pk_bf16_f32 %0, %1, %2" : "=v"(r) : "v"(a), "v"(b));
  return r;
}

// --- R8 asm pipeline primitives -------------------------------------------
#define GLD(D, PTR, OFF) \
  asm volatile("global_load_dwordx4 %0, %1, off offset:" #OFF \
               : "=v"(D) : "v"(PTR))

#define WAITV(N)                                              \
  do {                                                        \
    asm volatile("s_waitcnt vmcnt(" #N ")" ::: "memory");     \
    __builtin_amdgcn_sched_barrier(0);                        \
  } while (0)

#define ISSV(G, OFF)                                          \
  do {                                                        \
    GLD(vf[G][0], vpa, OFF); GLD(vf[G][1], vpb, OFF);         \
    GLD(vf[G][2], vpc, OFF); GLD(vf[G][3], vpd, OFF);         \
  } while (0)

#define ISSK()                                                \
  do {                                                        \
    kp0 += 32768; kp1 += 32768;                               \
    GLD(kf[0][0], kp0, 0);  GLD(kf[0][1], kp0, 32);           \
    GLD(kf[0][2], kp0, 64); GLD(kf[0][3], kp0, 96);           \
    GLD(kf[1][0], kp1, 0);  GLD(kf[1][1], kp1, 32);           \
    GLD(kf[1][2], kp1, 64); GLD(kf[1][3], kp1, 96);           \
  } while (0)

#define PVSTEP(KS)                                                             \
  do {                                                                         \
    const int kb = 64 * (KS) + 16 * lg;                                        \
    short8 pf0 = *(const short8*)(Pb + (lc) * 512      + (kb ^ (lc << 4)));    \
    short8 pf1 = *(const short8*)(Pb + (16 + lc) * 512 + (kb ^ ((16 + lc) << 4))); \
    short8 pf2 = *(const short8*)(Pb + (32 + lc) * 512 + (kb ^ (lc << 4)));    \
    short8 pf3 = *(const short8*)(Pb + (48 + lc) * 512 + (kb ^ ((16 + lc) << 4))); \
    __builtin_amdgcn_s_setprio(1);                                             \
    acc16[0][0] = __builtin_amdgcn_mfma_f32_16x16x32_bf16(pf0, vf[KS][0], acc16[0][0], 0, 0, 0); \
    acc16[1][0] = __builtin_amdgcn_mfma_f32_16x16x32_bf16(pf1, vf[KS][0], acc16[1][0], 0, 0, 0); \
    acc16[2][0] = __builtin_amdgcn_mfma_f32_16x16x32_bf16(pf2, vf[KS][0], acc16[2][0], 0, 0, 0); \
    acc16[3][0] = __builtin_amdgcn_mfma_f32_16x16x32_bf16(pf3, vf[KS][0], acc16[3][0], 0, 0, 0); \
    acc16[0][1] = __builtin_amdgcn_mfma_f32_16x16x32_bf16(pf0, vf[KS][1], acc16[0][1], 0, 0, 0); \
    acc16[1][1] = __builtin_amdgcn_mfma_f32_16x16x32_bf16(pf1, vf[KS][1], acc16[1][1], 0, 0, 0); \
    acc16[2][1] = __builtin_amdgcn_mfma_f32_16x16x32_bf16(pf2, vf[KS][1], acc16[2][1], 0, 0, 0); \
    acc16[3][1] = __builtin_amdgcn_mfma_f32_16x16x32_bf16(pf3, vf[KS][1], acc16[3][1], 0, 0, 0); \
    acc16[0][2] = __builtin_amdgcn_mfma_f32_16x16x32_bf16(pf0, vf[KS][2], acc16[0][2], 0, 0, 0); \
    acc16[1][2] = __builtin_amdgcn_mfma_f32_16x16x32_bf16(pf1, vf[KS][2], acc16[1][2], 0, 0, 0); \
    acc16[2][2] = __builtin_amdgcn_mfma_f32_16x16x32_bf16(pf2, vf[KS][2], acc16[2][2], 0, 0, 0); \
    acc16[3][2] = __builtin_amdgcn_mfma_f32_16x16x32_bf16(pf3, vf[KS][2], acc16[3][2], 0, 0, 0); \
    acc16[0][3] = __builtin_amdgcn_mfma_f32_16x16x32_bf16(pf0, vf[KS][3], acc16[0][3], 0, 0, 0); \
    acc16[1][3] = __builtin_amdgcn_mfma_f32_16x16x32_bf16(pf1, vf[KS][3], acc16[1][3], 0, 0, 0); \
    acc16[2][3] = __builtin_amdgcn_mfma_f32_16x16x32_bf16(pf2, vf[KS][3], acc16[2][3], 0, 0, 0); \
    acc16[3][3] = __builtin_amdgcn_mfma_f32_16x16x32_bf16(pf3, vf[KS][3], acc16[3][3], 0, 0, 0); \
    __builtin_amdgcn_s_setprio(0);                                             \
  } while (0)

// ---------------------------------------------------------------------------
// Kernel 1: weight prep.  W'[384][256] bf16 = [Wq*QSCL ; Wk ; Wv], bias'[384].
// ---------------------------------------------------------------------------
__global__ void prep_kernel(const float* __restrict__ Wq, const float* __restrict__ bq,
                            const float* __restrict__ Wk, const float* __restrict__ bk,
                            const float* __restrict__ Wv, const float* __restrict__ bv,
                            unsigned short* __restrict__ Wc, float* __restrict__ biasc) {
  int idx = blockIdx.x * 256 + threadIdx.x;
  if (idx < 384 * 256) {
    int ch = idx >> 8, c = idx & 255;
    float v;
    if (ch < 64)       v = Wq[ch * 256 + c] * QSCL;
    else if (ch < 128) v = Wk[(ch - 64) * 256 + c];
    else               v = Wv[(ch - 128) * 256 + c];
    Wc[idx] = bfb(v);
  }
  if (idx < 384) {
    float bb;
    if (idx < 64)       bb = bq[idx] * QSCL;
    else if (idx < 128) bb = bk[idx - 64];
    else                bb = bv[idx - 128];
    biasc[idx] = bb;
  }
}

// ---------------------------------------------------------------------------
// Kernel 2: projections.  Per (batch, 64-row n-block): stage x[256c][64n]
// transposed into LDS as bf16 (XOR-swizzled), then OUT[n][ch] = Xt * W'^T via
// 32x32x16 bf16 MFMA.  Outputs: Qt,Kt [B][N][64] (n-major), V [B][C][N].
// ---------------------------------------------------------------------------
__global__ __launch_bounds__(256, 2) void proj_kernel(
    const float* __restrict__ x, const unsigned short* __restrict__ Wc,
    const float* __restrict__ biasc, unsigned short* __restrict__ Qt,
    unsigned short* __restrict__ Kt, unsigned short* __restrict__ V) {
  __shared__ unsigned short XT[64 * 256];  // [n][c] bf16, swizzled, 32 KiB
  const int tid = threadIdx.x;
  const int b = blockIdx.y;
  const int n0 = blockIdx.x * 64;

  // stage: x[b][c][n0+0..63] fp32 -> XT[n][c] bf16 (transpose), swizzle:
  // ushort idx = n*256 + (((c>>3) ^ (n&15))<<3) + (c&7)
  {
    const f32x4* x4 = (const f32x4*)(x + ((size_t)b * C_) * N_ + n0);
    int c = tid >> 4;                  // 0..15 (+16 per pass)
    const int nl = (tid & 15) << 2;    // 0,4,...,60
#pragma unroll
    for (int p = 0; p < 16; ++p, c += 16) {
      f32x4 v = x4[(size_t)c * (N_ / 4) + (nl >> 2)];
#pragma unroll
      for (int i = 0; i < 4; ++i) {
        int n = nl + i;
        XT[n * 256 + ((((c >> 3) ^ (n & 15)) << 3) | (c & 7))] = bfb(v[i]);
      }
    }
  }
  __syncthreads();

  const int lane = tid & 63, li = lane & 31, hi = lane >> 5;
  const int w = tid >> 6;
  const int ch0 = 96 * w;  // this wave's 96 output channels (3 x 32)

  f32x16 acc[2][3];
#pragma unroll
  for (int mt = 0; mt < 2; ++mt)
#pragma unroll
    for (int j = 0; j < 3; ++j)
#pragma unroll
      for (int r = 0; r < 16; ++r) acc[mt][j][r] = 0.f;

  const short8* Wc8 = (const short8*)Wc;
#pragma unroll
  for (int ks = 0; ks < 16; ++ks) {
    // A-frags: lane holds Xt[n=32*mt+li][c=16*ks+8*hi .. +8]
    int chunk = 2 * ks + hi;
    short8 a0 = *(const short8*)&XT[(li) * 256 + ((chunk ^ (li & 15)) << 3)];
    short8 a1 = *(const short8*)&XT[(32 + li) * 256 + ((chunk ^ (li & 15)) << 3)];
#pragma unroll
    for (int j = 0; j < 3; ++j) {
      short8 bf = Wc8[(size_t)(ch0 + 32 * j + li) * 32 + chunk];
      acc[0][j] = __builtin_amdgcn_mfma_f32_32x32x16_bf16(a0, bf, acc[0][j], 0, 0, 0);
      acc[1][j] = __builtin_amdgcn_mfma_f32_32x32x16_bf16(a1, bf, acc[1][j], 0, 0, 0);
    }
  }

  // epilogue: D[row=n][col=ch], row = (r&3)+8*(r>>2)+4*hi + 32*mt, col = li
#pragma unroll
  for (int j = 0; j < 3; ++j) {
    const int chb = ch0 + 32 * j;  // wave-uniform 32-block, never straddles Q/K/V
    const int ch = chb + li;
    const float bias = biasc[ch];
#pragma unroll
    for (int mt = 0; mt < 2; ++mt) {
      if (chb < 64) {
#pragma unroll
        for (int r = 0; r < 16; ++r) {
          int n = n0 + 32 * mt + (r & 3) + 8 * (r >> 2) + 4 * hi;
          Qt[((size_t)(b * N_ + n) << 6) + ch] = bfb(acc[mt][j][r] + bias);
        }
      } else if (chb < 128) {
#pragma unroll
        for (int r = 0; r < 16; ++r) {
          int n = n0 + 32 * mt + (r & 3) + 8 * (r >> 2) + 4 * hi;
          Kt[((size_t)(b * N_ + n) << 6) + (ch - 64)] = bfb(acc[mt][j][r] + bias);
        }
      } else {
        const int cv = ch - 128;
#pragma unroll
        for (int q = 0; q < 4; ++q) {  // 4 consecutive n per 8B store
          short4v pk;
#pragma unroll
          for (int i = 0; i < 4; ++i) pk[i] = (short)bfb(acc[mt][j][4 * q + i] + bias);
          int n = n0 + 32 * mt + 8 * q + 4 * hi;
          *(short4v*)&V[(size_t)(b * C_ + cv) * N_ + n] = pk;
        }
      }
    }
  }
}

// ---------------------------------------------------------------------------
// Kernel 3: attention.  Grid 512 x 256 threads (4 waves).
// b = id & 7 (batch <-> XCD), m0 = (id >> 3) * 64.  kv-block 256, 16 iters.
// Phase 1(t): vmcnt(0) (drain K(t)); S for kv-slice [kv0+64w,+64) x 64 m
// (32x32 MFMA); exp2 + pack P bf16 -> swizzled LDS buf t&1; issue V groups
// 0..2 (asm); barrier.  Phase 2(t): 8 k-steps; per step issue V group ks+3
// (ks<5) or K(t+1) (ks5), counted vmcnt, 4x ds_read_b128 P, 16x 16x16x32
// MFMA.  Last iter peeled with tightened waits (no K issue, drains to 0).
// P byte addr: buf*32768 + m*512 + (kvbyte ^ ((m&31)<<4)).
// ---------------------------------------------------------------------------
__global__ __launch_bounds__(256, 2) void flash_kernel(
    const unsigned short* __restrict__ Qt, const unsigned short* __restrict__ Kt,
    const unsigned short* __restrict__ V, const float* __restrict__ x,
    const float* __restrict__ gamma, float* __restrict__ out) {
  __shared__ unsigned short P[2][64 * 256];  // 2 x 32 KiB, swizzled
  __shared__ float den_lds[4][2][32];

  const int tid = threadIdx.x;
  const int lane = tid & 63, li = lane & 31, hi = lane >> 5;
  const int lg = lane >> 4, lc = lane & 15;   // 16-lane group / in-group id
  const int w = tid >> 6;
  const int id = blockIdx.x;
  const int b = id & 7;                // batch == XCD (round-robin dispatch)
  const int m0 = (id >> 3) << 6;       // 64-row m-block

  const short8* Qt8 = (const short8*)Qt;

  // Q B-frags (32x32 QK): lane holds Qt[m0+32*mt+li][16*ks+8*hi .. +8]
  short8 qb[2][4];
#pragma unroll
  for (int mt = 0; mt < 2; ++mt)
#pragma unroll
    for (int ks = 0; ks < 4; ++ks)
      qb[mt][ks] = Qt8[((size_t)b * N_ + m0 + 32 * mt + li) * 8 + 2 * ks + hi];

  f32x4 acc16[4][4];  // [t16 m-subtile][ct c-subtile]
#pragma unroll
  for (int t16 = 0; t16 < 4; ++t16)
#pragma unroll
    for (int ct = 0; ct < 4; ++ct)
#pragma unroll
      for (int r = 0; r < 4; ++r) acc16[t16][ct][r] = 0.f;
  float den[2] = {0.f, 0.f};

  // V per-lane base pointers (ct = 0..3), advanced 512 B (256 kv) per iter
  const char* vpa = (const char*)(V + ((size_t)b * C_ + 64 * w + 0  + lc) * N_ + 8 * lg);
  const char* vpb = (const char*)(V + ((size_t)b * C_ + 64 * w + 16 + lc) * N_ + 8 * lg);
  const char* vpc = (const char*)(V + ((size_t)b * C_ + 64 * w + 32 + lc) * N_ + 8 * lg);
  const char* vpd = (const char*)(V + ((size_t)b * C_ + 64 * w + 48 + lc) * N_ + 8 * lg);
  // K per-lane base pointers (nt = 0/1): row = b*N + kv0 + 64w + 32nt + li
  const char* kp0 = (const char*)Kt + ((size_t)b * N_ + 64 * w + li) * 128 + hi * 16;
  const char* kp1 = kp0 + 32 * 128;

  short8 kf[2][4];
  short8 vf[8][4];

  // K(0) preamble
  GLD(kf[0][0], kp0, 0);  GLD(kf[0][1], kp0, 32);
  GLD(kf[0][2], kp0, 64); GLD(kf[0][3], kp0, 96);
  GLD(kf[1][0], kp1, 0);  GLD(kf[1][1], kp1, 32);
  GLD(kf[1][2], kp1, 64); GLD(kf[1][3], kp1, 96);

#pragma unroll 1
  for (int t = 0; t < 16; ++t) {
    char* Pb = (char*)P[t & 1];

    // ---- phase 1: drain K(t), S for kv-slice, pack P ----
    WAITV(0);
#pragma unroll
    for (int nt = 0; nt < 2; ++nt) {
#pragma unroll
      for (int mt = 0; mt < 2; ++mt) {
        f32x16 st;
#pragma unroll
        for (int r = 0; r < 16; ++r) st[r] = 0.f;
#pragma unroll
        for (int ks = 0; ks < 4; ++ks)
          st = __builtin_amdgcn_mfma_f32_32x32x16_bf16(kf[nt][ks], qb[mt][ks], st, 0, 0, 0);
        // S^T tile: lane holds m = 32*mt+li, kv_local = 64w+32nt+(r&3)+8*(r>>2)+4*hi
        float e[16];
        float ds = 0.f;
#pragma unroll
        for (int r = 0; r < 16; ++r) {
          e[r] = EXP2F(st[r]);
          ds += e[r];
        }
        den[mt] += ds;
        char* rp = Pb + (32 * mt + li) * 512;
        const int key = li << 4;
#pragma unroll
        for (int u = 0; u < 4; ++u) {
          unsigned lo = cvtpk(e[4 * u], e[4 * u + 1]);
          unsigned hh = cvtpk(e[4 * u + 2], e[4 * u + 3]);
          unsigned long long vv = (unsigned long long)lo | ((unsigned long long)hh << 32);
          int colbyte = 128 * w + 64 * nt + 16 * u + 8 * hi;
          *(unsigned long long*)(rp + (colbyte ^ key)) = vv;
        }
      }
    }

    // V groups 0..2 for this iter's PV (latency covered by barrier + steps)
    ISSV(0, 0);
    ISSV(1, 64);
    ISSV(2, 128);

    __syncthreads();  // P[t&1] ready

    // ---- phase 2: PV, 8 k-steps of 32 kv ----
    if (t < 15) {
      ISSV(3, 192); WAITV(12); PVSTEP(0);
      ISSV(4, 256); WAITV(12); PVSTEP(1);
      ISSV(5, 320); WAITV(12); PVSTEP(2);
      ISSV(6, 384); WAITV(12); PVSTEP(3);
      ISSV(7, 448); WAITV(12); PVSTEP(4);
      ISSK();       WAITV(16); PVSTEP(5);
                    WAITV(12); PVSTEP(6);
                    WAITV(8);  PVSTEP(7);
      vpa += 512; vpb += 512; vpc += 512; vpd += 512;
    } else {  // peeled tail: no K issue, drain to 0
      ISSV(3, 192); WAITV(12); PVSTEP(0);
      ISSV(4, 256); WAITV(12); PVSTEP(1);
      ISSV(5, 320); WAITV(12); PVSTEP(2);
      ISSV(6, 384); WAITV(12); PVSTEP(3);
      ISSV(7, 448); WAITV(12); PVSTEP(4);
                    WAITV(8);  PVSTEP(5);
                    WAITV(4);  PVSTEP(6);
                    WAITV(0);  PVSTEP(7);
    }
  }

  // ---- den reduction across waves ----
#pragma unroll
  for (int mt = 0; mt < 2; ++mt) {
    float dh = den[mt] + __shfl_xor(den[mt], 32);  // full m-row over wave's kv
    if (hi == 0) den_lds[w][mt][li] = dh;
  }
  __syncthreads();

  const float g = gamma[0];
  float ig0, ig1;
  {
    float d0 = den_lds[0][0][li] + den_lds[1][0][li] + den_lds[2][0][li] + den_lds[3][0][li];
    float d1 = den_lds[0][1][li] + den_lds[1][1][li] + den_lds[2][1][li] + den_lds[3][1][li];
    ig0 = g / d0;  // lane li: gamma/den for m-row m0+li
    ig1 = g / d1;  // m-row m0+32+li
  }

  // ---- epilogue: D row = 4*lg + r (consecutive m), col c = 16*ct + lc ----
#pragma unroll
  for (int t16 = 0; t16 < 4; ++t16) {
    f32x4 idn;
#pragma unroll
    for (int r = 0; r < 4; ++r)
      idn[r] = __shfl(t16 < 2 ? ig0 : ig1, 16 * (t16 & 1) + 4 * lg + r);
#pragma unroll
    for (int ct = 0; ct < 4; ++ct) {
      size_t off = ((size_t)b * C_ + 64 * w + 16 * ct + lc) * N_ + m0 + 16 * t16 + 4 * lg;
      f32x4 xv = *(const f32x4*)(x + off);
      f32x4 o;
#pragma unroll
      for (int r = 0; r < 4; ++r) o[r] = xv[r] + idn[r] * acc16[t16][ct][r];
      *(f32x4*)(out + off) = o;
    }
  }
}

// ---------------------------------------------------------------------------
extern "C" void kernel_launch(void* const* d_in, const int* in_sizes, int n_in,
                              void* d_out, int out_size, void* d_ws, size_t ws_size,
                              hipStream_t stream) {
  const float* x = (const float*)d_in[0];
  const float* Wq = (const float*)d_in[1];
  const float* bq = (const float*)d_in[2];
  const float* Wk = (const float*)d_in[3];
  const float* bk = (const float*)d_in[4];
  const float* Wv = (const float*)d_in[5];
  const float* bv = (const float*)d_in[6];
  const float* gamma = (const float*)d_in[7];
  float* out = (float*)d_out;

  char* ws = (char*)d_ws;
  unsigned short* Wc = (unsigned short*)(ws);                    // 196608 B
  float* biasc = (float*)(ws + 196608);                          // 1536 B
  unsigned short* Qt = (unsigned short*)(ws + 198144);           // 4 MiB
  unsigned short* Kt = (unsigned short*)(ws + 198144 + 4194304); // 4 MiB
  unsigned short* Vv = (unsigned short*)(ws + 198144 + 8388608); // 16 MiB
  // total ws use: ~25.4 MB

  prep_kernel<<<384, 256, 0, stream>>>(Wq, bq, Wk, bk, Wv, bv, Wc, biasc);
  proj_kernel<<<dim3(64, 8), 256, 0, stream>>>(x, Wc, biasc, Qt, Kt, Vv);
  flash_kernel<<<512, 256, 0, stream>>>(Qt, Kt, Vv, x, gamma, out);
}

// Round 9
// 189.829 us; speedup vs baseline: 3.2642x; 3.2642x over previous
//
#include <hip/hip_runtime.h>

// Self-attention block (non-local): B=8, C=256, H=W=64 -> N=4096, dk=64.
// out = x + gamma * softmax((Wq x)^T (Wk x) / 8) applied to (Wv x).
// Pipeline: prep (weights->bf16, fold log2e/8 into Wq) -> proj (MFMA GEMM,
// in-LDS transpose of x) -> flash.
// R9 flash: kv-block 64, wave kv-slice 16, S via 16x16x32 MFMA.  V never
// touches LDS: 8 V-frags (32 VGPR) loaded at top of region A, consumed after
// the barrier (barrier = fence: cannot sink; 32 regs: does not spill).  Only
// P crosses LDS: 2x8KB double-buffered XOR-swizzled, ONE barrier/iter.
// Max-free softmax (logits O(1) by construction), direct f32x4 epilogue.

typedef __attribute__((ext_vector_type(8)))  short short8;
typedef __attribute__((ext_vector_type(4)))  short short4v;
typedef __attribute__((ext_vector_type(16))) float f32x16;
typedef __attribute__((ext_vector_type(4)))  float f32x4;

#define B_   8
#define C_   256
#define N_   4096
#define DK_  64
// log2(e) / sqrt(dk) = 1.4426950408889634 / 8
#define QSCL 0.18033688011112043f

#if defined(__has_builtin)
#if __has_builtin(__builtin_amdgcn_exp2f)
#define EXP2F(x) __builtin_amdgcn_exp2f(x)
#else
#define EXP2F(x) exp2f(x)
#endif
#else
#define EXP2F(x) exp2f(x)
#endif

// float -> bf16 bits, round-to-nearest-even (inputs are finite; no NaN path)
__device__ __forceinline__ unsigned short bfb(float f) {
  unsigned u = __builtin_bit_cast(unsigned, f);
  unsigned r = (u + 0x7fffu + ((u >> 16) & 1u)) >> 16;
  return (unsigned short)r;
}

// packed f32x2 -> bf16x2 (low = a, high = b), RNE
__device__ __forceinline__ unsigned cvtpk(float a, float b) {
  unsigned r;
  asm("v_cvt_pk_bf16_f32 %0, %1, %2" : "=v"(r) : "v"(a), "v"(b));
  return r;
}

// ---------------------------------------------------------------------------
// Kernel 1: weight prep.  W'[384][256] bf16 = [Wq*QSCL ; Wk ; Wv], bias'[384].
// ---------------------------------------------------------------------------
__global__ void prep_kernel(const float* __restrict__ Wq, const float* __restrict__ bq,
                            const float* __restrict__ Wk, const float* __restrict__ bk,
                            const float* __restrict__ Wv, const float* __restrict__ bv,
                            unsigned short* __restrict__ Wc, float* __restrict__ biasc) {
  int idx = blockIdx.x * 256 + threadIdx.x;
  if (idx < 384 * 256) {
    int ch = idx >> 8, c = idx & 255;
    float v;
    if (ch < 64)       v = Wq[ch * 256 + c] * QSCL;
    else if (ch < 128) v = Wk[(ch - 64) * 256 + c];
    else               v = Wv[(ch - 128) * 256 + c];
    Wc[idx] = bfb(v);
  }
  if (idx < 384) {
    float bb;
    if (idx < 64)       bb = bq[idx] * QSCL;
    else if (idx < 128) bb = bk[idx - 64];
    else                bb = bv[idx - 128];
    biasc[idx] = bb;
  }
}

// ---------------------------------------------------------------------------
// Kernel 2: projections.  Per (batch, 64-row n-block): stage x[256c][64n]
// transposed into LDS as bf16 (XOR-swizzled), then OUT[n][ch] = Xt * W'^T via
// 32x32x16 bf16 MFMA.  Outputs: Qt,Kt [B][N][64] (n-major), V [B][C][N].
// ---------------------------------------------------------------------------
__global__ __launch_bounds__(256, 2) void proj_kernel(
    const float* __restrict__ x, const unsigned short* __restrict__ Wc,
    const float* __restrict__ biasc, unsigned short* __restrict__ Qt,
    unsigned short* __restrict__ Kt, unsigned short* __restrict__ V) {
  __shared__ unsigned short XT[64 * 256];  // [n][c] bf16, swizzled, 32 KiB
  const int tid = threadIdx.x;
  const int b = blockIdx.y;
  const int n0 = blockIdx.x * 64;

  // stage: x[b][c][n0+0..63] fp32 -> XT[n][c] bf16 (transpose), swizzle:
  // ushort idx = n*256 + (((c>>3) ^ (n&15))<<3) + (c&7)
  {
    const f32x4* x4 = (const f32x4*)(x + ((size_t)b * C_) * N_ + n0);
    int c = tid >> 4;                  // 0..15 (+16 per pass)
    const int nl = (tid & 15) << 2;    // 0,4,...,60
#pragma unroll
    for (int p = 0; p < 16; ++p, c += 16) {
      f32x4 v = x4[(size_t)c * (N_ / 4) + (nl >> 2)];
#pragma unroll
      for (int i = 0; i < 4; ++i) {
        int n = nl + i;
        XT[n * 256 + ((((c >> 3) ^ (n & 15)) << 3) | (c & 7))] = bfb(v[i]);
      }
    }
  }
  __syncthreads();

  const int lane = tid & 63, li = lane & 31, hi = lane >> 5;
  const int w = tid >> 6;
  const int ch0 = 96 * w;  // this wave's 96 output channels (3 x 32)

  f32x16 acc[2][3];
#pragma unroll
  for (int mt = 0; mt < 2; ++mt)
#pragma unroll
    for (int j = 0; j < 3; ++j)
#pragma unroll
      for (int r = 0; r < 16; ++r) acc[mt][j][r] = 0.f;

  const short8* Wc8 = (const short8*)Wc;
#pragma unroll
  for (int ks = 0; ks < 16; ++ks) {
    // A-frags: lane holds Xt[n=32*mt+li][c=16*ks+8*hi .. +8]
    int chunk = 2 * ks + hi;
    short8 a0 = *(const short8*)&XT[(li) * 256 + ((chunk ^ (li & 15)) << 3)];
    short8 a1 = *(const short8*)&XT[(32 + li) * 256 + ((chunk ^ (li & 15)) << 3)];
#pragma unroll
    for (int j = 0; j < 3; ++j) {
      short8 bf = Wc8[(size_t)(ch0 + 32 * j + li) * 32 + chunk];
      acc[0][j] = __builtin_amdgcn_mfma_f32_32x32x16_bf16(a0, bf, acc[0][j], 0, 0, 0);
      acc[1][j] = __builtin_amdgcn_mfma_f32_32x32x16_bf16(a1, bf, acc[1][j], 0, 0, 0);
    }
  }

  // epilogue: D[row=n][col=ch], row = (r&3)+8*(r>>2)+4*hi + 32*mt, col = li
#pragma unroll
  for (int j = 0; j < 3; ++j) {
    const int chb = ch0 + 32 * j;  // wave-uniform 32-block, never straddles Q/K/V
    const int ch = chb + li;
    const float bias = biasc[ch];
#pragma unroll
    for (int mt = 0; mt < 2; ++mt) {
      if (chb < 64) {
#pragma unroll
        for (int r = 0; r < 16; ++r) {
          int n = n0 + 32 * mt + (r & 3) + 8 * (r >> 2) + 4 * hi;
          Qt[((size_t)(b * N_ + n) << 6) + ch] = bfb(acc[mt][j][r] + bias);
        }
      } else if (chb < 128) {
#pragma unroll
        for (int r = 0; r < 16; ++r) {
          int n = n0 + 32 * mt + (r & 3) + 8 * (r >> 2) + 4 * hi;
          Kt[((size_t)(b * N_ + n) << 6) + (ch - 64)] = bfb(acc[mt][j][r] + bias);
        }
      } else {
        const int cv = ch - 128;
#pragma unroll
        for (int q = 0; q < 4; ++q) {  // 4 consecutive n per 8B store
          short4v pk;
#pragma unroll
          for (int i = 0; i < 4; ++i) pk[i] = (short)bfb(acc[mt][j][4 * q + i] + bias);
          int n = n0 + 32 * mt + 8 * q + 4 * hi;
          *(short4v*)&V[(size_t)(b * C_ + cv) * N_ + n] = pk;
        }
      }
    }
  }
}

// ---------------------------------------------------------------------------
// Kernel 3: attention.  Grid 512 x 256 threads (4 waves).
// b = id & 7 (batch <-> XCD), m0 = (id >> 3) * 64.  kv-block 64, 64 iters.
// Region A(t): load this iter's V frags (8 x 16B -> 32 VGPR, consumed after
// the barrier) + K frags (2 x 16B); S for the wave's 16-kv slice x 64 m via
// 16x16x32 MFMA (A=K: row=kv_local=lane&15, k=dk=8*(lane>>4)+j; B=Q:
// col=m_local); exp2 + cvtpk -> one 8B P store per mt.  __syncthreads.
// Region B(t): PV 16x16x32, P A-frags from swizzled LDS, V from regs.
// P byte addr: buf*8192 + m*128 + (kvbyte ^ ((m&7)<<4)); one barrier/iter
// (P double-buffered: BAR(t+1) orders B(t) reads before A(t+2) writes).
// ---------------------------------------------------------------------------
__global__ __launch_bounds__(256, 2) void flash_kernel(
    const unsigned short* __restrict__ Qt, const unsigned short* __restrict__ Kt,
    const unsigned short* __restrict__ V, const float* __restrict__ x,
    const float* __restrict__ gamma, float* __restrict__ out) {
  __shared__ unsigned short P[2][64 * 64];  // 2 x 8 KiB, swizzled
  __shared__ float den_lds[4][4][16];       // [wave][mt][lc]

  const int tid = threadIdx.x;
  const int lane = tid & 63;
  const int lc = lane & 15, lg = lane >> 4;
  const int w = tid >> 6;
  const int id = blockIdx.x;
  const int b = id & 7;                // batch == XCD (round-robin dispatch)
  const int m0 = (id >> 3) << 6;       // 64-row m-block

  // Q B-frags: qb[mt][ks] = Q[m0+16mt+lc][dk = 32ks+8lg .. +7]
  short8 qb[4][2];
#pragma unroll
  for (int mt = 0; mt < 4; ++mt)
#pragma unroll
    for (int ks = 0; ks < 2; ++ks)
      qb[mt][ks] = *(const short8*)(Qt + ((size_t)b * N_ + m0 + 16 * mt + lc) * 64 +
                                    32 * ks + 8 * lg);

  f32x4 acc16[4][4];  // [t16 m-subtile][ct c-subtile]
#pragma unroll
  for (int t16 = 0; t16 < 4; ++t16)
#pragma unroll
    for (int ct = 0; ct < 4; ++ct)
#pragma unroll
      for (int r = 0; r < 4; ++r) acc16[t16][ct][r] = 0.f;
  float den[4] = {0.f, 0.f, 0.f, 0.f};

  // K base: row kv = kv0 + 16w + lc, dk bytes 16lg + {0,64}; +8192B per iter
  const char* Kp = (const char*)Kt + ((size_t)b * N_ + 16 * w + lc) * 128 + 16 * lg;
  // V row pointers: c = 64w + 16ct + lc, kv elem 8lg; +128B per iter
  const unsigned short* vp[4];
#pragma unroll
  for (int ct = 0; ct < 4; ++ct)
    vp[ct] = V + ((size_t)b * C_ + 64 * w + 16 * ct + lc) * N_ + 8 * lg;

  const int pkey = (lc & 7) << 4;      // P swizzle key (m&7 == lc&7)
  const int pwcol = (32 * w + 8 * lg) ^ pkey;  // P-write column byte

#pragma unroll 2
  for (int t = 0; t < 64; ++t) {
    const int kv0 = t << 6;
    char* Pb = (char*)P[t & 1];

    // ---- region A: V frags for B(t) (ride regs across the barrier) ----
    short8 vf[2][4];
#pragma unroll
    for (int ks = 0; ks < 2; ++ks)
#pragma unroll
      for (int ct = 0; ct < 4; ++ct)
        vf[ks][ct] = *(const short8*)(vp[ct] + kv0 + 32 * ks);
    // K frags for this iter's S
    short8 kf0 = *(const short8*)(Kp + (size_t)t * 8192);
    short8 kf1 = *(const short8*)(Kp + (size_t)t * 8192 + 64);
    asm volatile("" ::: "memory");  // pin loads above the compute

    // ---- S: 16kv x 64m, 4 m-tiles x (K=32 x 2) ----
#pragma unroll
    for (int mt = 0; mt < 4; ++mt) {
      f32x4 st = {0.f, 0.f, 0.f, 0.f};
      st = __builtin_amdgcn_mfma_f32_16x16x32_bf16(kf0, qb[mt][0], st, 0, 0, 0);
      st = __builtin_amdgcn_mfma_f32_16x16x32_bf16(kf1, qb[mt][1], st, 0, 0, 0);
      // lane holds S[kv = kv0+16w+4lg+r][m = m0+16mt+lc], r=0..3
      float e0 = EXP2F(st[0]), e1 = EXP2F(st[1]);
      float e2 = EXP2F(st[2]), e3 = EXP2F(st[3]);
      den[mt] += (e0 + e1) + (e2 + e3);
      unsigned lo = cvtpk(e0, e1), hh = cvtpk(e2, e3);
      unsigned long long vv = (unsigned long long)lo | ((unsigned long long)hh << 32);
      *(unsigned long long*)(Pb + (16 * mt + lc) * 128 + pwcol) = vv;
    }

    __syncthreads();  // P[t&1] ready; V/K regs ride across

    // ---- region B: PV (16x16x32), 2 k-steps of 32 kv ----
#pragma unroll
    for (int ks = 0; ks < 2; ++ks) {
      short8 pf[4];
#pragma unroll
      for (int t16 = 0; t16 < 4; ++t16)
        pf[t16] = *(const short8*)(Pb + (16 * t16 + lc) * 128 +
                                   ((64 * ks + 16 * lg) ^ pkey));
      __builtin_amdgcn_s_setprio(1);
#pragma unroll
      for (int ct = 0; ct < 4; ++ct)
#pragma unroll
        for (int t16 = 0; t16 < 4; ++t16)
          acc16[t16][ct] = __builtin_amdgcn_mfma_f32_16x16x32_bf16(
              pf[t16], vf[ks][ct], acc16[t16][ct], 0, 0, 0);
      __builtin_amdgcn_s_setprio(0);
    }
    // no second barrier: P dbuf; BAR(t+1) orders B(t) before A(t+2)
  }

  // ---- den reduction: lg-groups (shfl) then cross-wave (LDS) ----
#pragma unroll
  for (int mt = 0; mt < 4; ++mt) {
    float d = den[mt];
    d += __shfl_xor(d, 16);
    d += __shfl_xor(d, 32);
    if (lg == 0) den_lds[w][mt][lc] = d;
  }
  __syncthreads();

  const float g = gamma[0];
  float ig[4];
#pragma unroll
  for (int mt = 0; mt < 4; ++mt) {
    float dtot = den_lds[0][mt][lc] + den_lds[1][mt][lc] +
                 den_lds[2][mt][lc] + den_lds[3][mt][lc];
    ig[mt] = g / dtot;  // lane's lc: gamma/den for m-row m0+16mt+lc
  }

  // ---- epilogue: lane holds O[m=16t16+4lg+r][c=16ct+lc]; f32x4 over m ----
#pragma unroll
  for (int t16 = 0; t16 < 4; ++t16) {
    f32x4 idn;
#pragma unroll
    for (int r = 0; r < 4; ++r)
      idn[r] = __shfl(ig[t16], 4 * lg + r);
#pragma unroll
    for (int ct = 0; ct < 4; ++ct) {
      size_t off = ((size_t)b * C_ + 64 * w + 16 * ct + lc) * N_ + m0 + 16 * t16 + 4 * lg;
      f32x4 xv = *(const f32x4*)(x + off);
      f32x4 o;
#pragma unroll
      for (int r = 0; r < 4; ++r) o[r] = xv[r] + idn[r] * acc16[t16][ct][r];
      *(f32x4*)(out + off) = o;
    }
  }
}

// ---------------------------------------------------------------------------
extern "C" void kernel_launch(void* const* d_in, const int* in_sizes, int n_in,
                              void* d_out, int out_size, void* d_ws, size_t ws_size,
                              hipStream_t stream) {
  const float* x = (const float*)d_in[0];
  const float* Wq = (const float*)d_in[1];
  const float* bq = (const float*)d_in[2];
  const float* Wk = (const float*)d_in[3];
  const float* bk = (const float*)d_in[4];
  const float* Wv = (const float*)d_in[5];
  const float* bv = (const float*)d_in[6];
  const float* gamma = (const float*)d_in[7];
  float* out = (float*)d_out;

  char* ws = (char*)d_ws;
  unsigned short* Wc = (unsigned short*)(ws);                    // 196608 B
  float* biasc = (float*)(ws + 196608);                          // 1536 B
  unsigned short* Qt = (unsigned short*)(ws + 198144);           // 4 MiB
  unsigned short* Kt = (unsigned short*)(ws + 198144 + 4194304); // 4 MiB
  unsigned short* Vv = (unsigned short*)(ws + 198144 + 8388608); // 16 MiB
  // total ws use: ~25.4 MB

  prep_kernel<<<384, 256, 0, stream>>>(Wq, bq, Wk, bk, Wv, bv, Wc, biasc);
  proj_kernel<<<dim3(64, 8), 256, 0, stream>>>(x, Wc, biasc, Qt, Kt, Vv);
  flash_kernel<<<512, 256, 0, stream>>>(Qt, Kt, Vv, x, gamma, out);
}